// Round 7
// baseline (353.114 us; speedup 1.0000x reference)
//
#include <hip/hip_runtime.h>
#include <hip/hip_bf16.h>
#include <math.h>

#define TOKENS 2048
#define HID 2048
#define FFN 1024
#define NEXP 16
#define NTOT 32
#define KSEL 4
#define RSCALE 2.5f

typedef __bf16 v8bf __attribute__((ext_vector_type(8)));
typedef __bf16 v4bf __attribute__((ext_vector_type(4)));
typedef float v4f __attribute__((ext_vector_type(4)));
typedef unsigned short u16x8v __attribute__((ext_vector_type(8)));

static __device__ __forceinline__ v8bf zero_v8bf() {
  u16x8v z = {0, 0, 0, 0, 0, 0, 0, 0};
  return __builtin_bit_cast(v8bf, z);
}

// Swizzled LDS addressing: row-major [rows][64] bf16 (128B rows, 8 chunks of
// 16B). Physical chunk = chunk ^ (row&7). Conflict-free on b128 frag reads
// (verified SQ_LDS_BANK_CONFLICT==0, rounds 2-6).
static __device__ __forceinline__ int swz(int row, int chunk) {
  return (row << 6) + ((((unsigned)(chunk ^ row)) & 7u) << 3);
}

// ---------------------------------------------------------------------------
// Router: one block per token. Exact fp32 logits -> softmax -> bias-corrected
// top-4 (lowest-index tie-break), zero-expert folding, writes
// out = zero_total*x, bf16 hidden copy, per-expert (token,weight) lists.
// ---------------------------------------------------------------------------
__global__ __launch_bounds__(256) void router_kernel(
    const float* __restrict__ hidden, const float* __restrict__ rw,
    const float* __restrict__ bias, float* __restrict__ out,
    __bf16* __restrict__ hbf,
    int* __restrict__ counts, int* __restrict__ pair_token,
    float* __restrict__ pair_weight)
{
  const int t = blockIdx.x;
  const int tid = threadIdx.x;
  __shared__ float sh[HID];
  __shared__ float part[8][NTOT];
  __shared__ float s_zt;

  const float* hrow = hidden + (size_t)t * HID;
  for (int i = tid; i < HID / 4; i += 256)
    ((float4*)sh)[i] = ((const float4*)hrow)[i];
  __syncthreads();

  {
    const int base = tid * 8;
    v8bf v;
#pragma unroll
    for (int j = 0; j < 8; ++j) v[j] = (__bf16)sh[base + j];
    *(v8bf*)(hbf + (size_t)t * HID + base) = v;
  }

  {
    const int g = tid >> 5, e = tid & 31;
    const float* w = rw + (size_t)e * HID + g * 256;
    const float* hh = sh + g * 256;
    float acc = 0.f;
#pragma unroll 8
    for (int h = 0; h < 256; ++h) acc = fmaf(hh[h], w[h], acc);
    part[g][e] = acc;
  }
  __syncthreads();

  if (tid < 64) {
    const int lane = tid;
    float logit = -INFINITY;
    if (lane < NTOT) {
      float s = 0.f;
#pragma unroll
      for (int g = 0; g < 8; ++g) s += part[g][lane];
      logit = s;
    }
    float m = logit;
#pragma unroll
    for (int off = 32; off; off >>= 1) m = fmaxf(m, __shfl_xor(m, off));
    const float ex = (lane < NTOT) ? expf(logit - m) : 0.f;
    float sum = ex;
#pragma unroll
    for (int off = 32; off; off >>= 1) sum += __shfl_xor(sum, off);
    float sc = (lane < NTOT) ? (ex / sum + bias[lane]) : -INFINITY;

    float zt = 0.f;
#pragma unroll
    for (int it = 0; it < KSEL; ++it) {
      float v = sc; int vid = lane;
#pragma unroll
      for (int off = 32; off; off >>= 1) {
        const float ov = __shfl_xor(v, off);
        const int oid = __shfl_xor(vid, off);
        if (ov > v || (ov == v && oid < vid)) { v = ov; vid = oid; }
      }
      const float wv = v * RSCALE;
      if (vid >= NEXP) {
        zt += wv;
      } else if (lane == 0) {
        const int pos = atomicAdd(&counts[vid], 1);
        pair_token[vid * TOKENS + pos] = t;
        pair_weight[vid * TOKENS + pos] = wv;
      }
      if (lane == vid) sc = -INFINITY;
    }
    if (lane == 0) s_zt = zt;
  }
  __syncthreads();

  const float zt = s_zt;
  float* orow = out + (size_t)t * HID;
  for (int i = tid; i < HID / 4; i += 256) {
    float4 v = ((const float4*)sh)[i];
    v.x *= zt; v.y *= zt; v.z *= zt; v.w *= zt;
    ((float4*)orow)[i] = v;
  }
}

// ---------------------------------------------------------------------------
__global__ void scan_kernel(const int* __restrict__ counts,
                            int* __restrict__ offsets) {
  if (threadIdx.x == 0) {
    int acc = 0;
#pragma unroll
    for (int e = 0; e < NEXP; ++e) { offsets[e] = acc; acc += counts[e]; }
    offsets[NEXP] = acc;
  }
}

// ---------------------------------------------------------------------------
// GEMM1 (grouped): tile = 64 gathered rows x 64 f-cols (gate AND up), BK=64.
// Expert-pinned XCD decode: e = ehi*8 + xcd -> each expert's full gemm1
// (w13[e], its hbf rows) lives on ONE XCD: w13 fetched from HBM once,
// mt re-reads of B-strips are L2 hits. Working blocks ~1024 = 4/CU.
// B staging: 8x dwordx4 f-contiguous + in-thread 4x8 transpose + 4x b128.
// ---------------------------------------------------------------------------
__global__ __launch_bounds__(256, 4) void gemm1_kernel(
    const __bf16* __restrict__ hbf, const float* __restrict__ w13,
    const int* __restrict__ counts, const int* __restrict__ offsets,
    const int* __restrict__ pair_token, const float* __restrict__ pair_weight,
    __bf16* __restrict__ act)
{
  const int lin = blockIdx.x;
  const int xcd = lin & 7;
  const int q = lin >> 3;        // 0..1023
  const int d = q & 511;         // dense = mt + 32*ft (mt fastest: the ~4
  const int ehi = q >> 9;        //   working mt of one ft co-schedule)
  const int mt = d & 31;
  const int ft = d >> 5;         // 0..15
  const int e = ehi * 8 + xcd;

  const int cnt = counts[e];
  const int m0 = mt * 64;
  if (m0 >= cnt) return;
  const int obase = offsets[e];
  const int fbase = ft * 64;

  __shared__ __bf16 sA[64 * 64];    // [m][k]   8 KB
  __shared__ __bf16 sB[128 * 64];   // [f'][k] 16 KB; rows 0-63 gate, 64-127 up
  __shared__ int sTok[64];
  __shared__ float sW[64];

  const int tid = threadIdx.x;
  if (tid < 64) {
    const int m = m0 + tid;
    sTok[tid] = (m < cnt) ? pair_token[e * TOKENS + m] : -1;
    sW[tid] = (m < cnt) ? pair_weight[e * TOKENS + m] : 0.f;
  }
  __syncthreads();

  const int wid = tid >> 6, lane = tid & 63;
  const int wr = wid >> 1, wf = wid & 1;
  const int lrow = lane & 15, lq = lane >> 4;

  // A staging: 4 threads/row, 2 chunks (32B) each
  const int ar = tid >> 2, ac = (tid & 3) * 2;
  const int a_tok = sTok[ar];
  const __bf16* a_src =
      (a_tok >= 0) ? (hbf + (size_t)a_tok * HID + ac * 8) : nullptr;

  // B staging: rg = tid&31 owns rows rg*4..rg*4+3 (rg<16: gate, else up);
  // kg = tid>>5 owns k-chunk kg*8..kg*8+7. 8 f-contiguous dwordx4 loads,
  // in-thread 4x8 transpose, 4 b128 swizzled writes.
  const int rg = tid & 31, kg = tid >> 5;
  const int brow0 = rg * 4;
  const int fb = (rg < 16) ? (fbase + rg * 4) : (FFN + fbase + (rg - 16) * 4);
  const float* b_ptr = w13 + (size_t)e * HID * (2 * FFN)
                     + (size_t)(kg * 8) * (2 * FFN) + fb;

  v4f accg[2][2], accu[2][2];
#pragma unroll
  for (int mi = 0; mi < 2; ++mi)
#pragma unroll
    for (int fi = 0; fi < 2; ++fi) {
      v4f z = {0.f, 0.f, 0.f, 0.f};
      accg[mi][fi] = z; accu[mi][fi] = z;
    }

  for (int kt = 0; kt < HID; kt += 64) {
    // ---- issue all staging loads (8 B-dwordx4 + 2 A-b128 in flight) ----
    float pb[8][4];
    {
      const float* src = b_ptr + (size_t)kt * (2 * FFN);
#pragma unroll
      for (int j = 0; j < 8; ++j)
        *(float4*)pb[j] = *(const float4*)(src + (size_t)j * (2 * FFN));
    }
    v8bf pa0, pa1;
    if (a_tok >= 0) {
      const v8bf* s = (const v8bf*)(a_src + kt);
      pa0 = s[0]; pa1 = s[1];
    } else {
      pa0 = zero_v8bf(); pa1 = zero_v8bf();
    }
    // ---- convert + LDS write ----
    *(v8bf*)&sA[swz(ar, ac)] = pa0;
    *(v8bf*)&sA[swz(ar, ac + 1)] = pa1;
#pragma unroll
    for (int i = 0; i < 4; ++i) {
      v8bf v;
#pragma unroll
      for (int j = 0; j < 8; ++j) v[j] = (__bf16)pb[j][i];
      *(v8bf*)&sB[swz(brow0 + i, kg)] = v;
    }
    __syncthreads();

#pragma unroll
    for (int ks = 0; ks < 2; ++ks) {
      v8bf a[2], bg[2], bu[2];
#pragma unroll
      for (int mi = 0; mi < 2; ++mi)
        a[mi] = *(const v8bf*)&sA[swz(wr * 32 + mi * 16 + lrow, ks * 4 + lq)];
#pragma unroll
      for (int fi = 0; fi < 2; ++fi) {
        bg[fi] = *(const v8bf*)&sB[swz(wf * 32 + fi * 16 + lrow, ks * 4 + lq)];
        bu[fi] = *(const v8bf*)&sB[swz(64 + wf * 32 + fi * 16 + lrow, ks * 4 + lq)];
      }
#pragma unroll
      for (int mi = 0; mi < 2; ++mi)
#pragma unroll
        for (int fi = 0; fi < 2; ++fi) {
          accg[mi][fi] = __builtin_amdgcn_mfma_f32_16x16x32_bf16(
              a[mi], bg[fi], accg[mi][fi], 0, 0, 0);
          accu[mi][fi] = __builtin_amdgcn_mfma_f32_16x16x32_bf16(
              a[mi], bu[fi], accu[mi][fi], 0, 0, 0);
        }
    }
    __syncthreads();
  }

  // ---- epilogue: swiglu, fold routing weight, store act (bf16) ----
#pragma unroll
  for (int mi = 0; mi < 2; ++mi) {
#pragma unroll
    for (int fi = 0; fi < 2; ++fi) {
      const int f = fbase + wf * 32 + fi * 16 + lrow;
#pragma unroll
      for (int r = 0; r < 4; ++r) {
        const int lr = wr * 32 + mi * 16 + lq * 4 + r;
        const int m = m0 + lr;
        if (m < cnt) {
          const float gg = accg[mi][fi][r];
          const float uu = accu[mi][fi][r];
          const float sg = gg / (1.f + __expf(-gg));
          act[(size_t)(obase + m) * FFN + f] = (__bf16)(sg * uu * sW[lr]);
        }
      }
    }
  }
}

// ---------------------------------------------------------------------------
// GEMM2 (grouped): tile = 128 gathered rows x 64 n-cols, BK=64.
// Expert-pinned XCD decode -> w2[e] AND act[e] rows stay on one XCD's L2.
// B staging: 4x dwordx4 n-contiguous + in-thread 4x4 transpose + 4x b64.
// atomicAdd into out (routing weight already folded into act).
// ---------------------------------------------------------------------------
__global__ __launch_bounds__(256, 4) void gemm2_kernel(
    const __bf16* __restrict__ act, const float* __restrict__ w2,
    const int* __restrict__ counts, const int* __restrict__ offsets,
    const int* __restrict__ pair_token, float* __restrict__ out)
{
  const int lin = blockIdx.x;
  const int xcd = lin & 7;
  const int q = lin >> 3;        // 0..1023
  const int d = q & 511;         // dense = mt + 16*nt (mt fastest)
  const int ehi = q >> 9;
  const int mt = d & 15;
  const int nt = d >> 4;         // 0..31
  const int e = ehi * 8 + xcd;

  const int cnt = counts[e];
  const int m0 = mt * 128;
  if (m0 >= cnt) return;
  const int obase = offsets[e];
  const int n0 = nt * 64;

  __shared__ __bf16 sA[128 * 64];   // [m][k] 16 KB
  __shared__ __bf16 sB[64 * 64];    // [n][k]  8 KB
  __shared__ int sTok[128];

  const int tid = threadIdx.x;
  if (tid < 128) {
    const int m = m0 + tid;
    sTok[tid] = (m < cnt) ? pair_token[e * TOKENS + m] : -1;
  }
  __syncthreads();

  const int wid = tid >> 6, lane = tid & 63;
  const int wr = wid >> 1, wf = wid & 1;
  const int lrow = lane & 15, lq = lane >> 4;

  // A staging: 2 threads/row, 4 chunks (64B) each
  const int ar = tid >> 1, ac4 = (tid & 1) * 4;
  const bool avalid = (m0 + ar) < cnt;
  const __bf16* a_src =
      avalid ? (act + (size_t)(obase + m0 + ar) * FFN + ac4 * 8) : nullptr;

  // B staging: rg = tid&15 owns rows rg*4..rg*4+3; kg = tid>>4 (0..15) owns
  // k mini-chunk kg*4..kg*4+3. 4 n-contiguous dwordx4, 4x4 transpose, 4 b64.
  const int rg = tid & 15, kg = tid >> 4;
  const int brow0 = rg * 4;
  const float* b_ptr = w2 + (size_t)e * FFN * HID
                     + (size_t)(kg * 4) * HID + n0 + rg * 4;

  v4f acc[4][2];
#pragma unroll
  for (int mi = 0; mi < 4; ++mi)
#pragma unroll
    for (int ni = 0; ni < 2; ++ni) {
      v4f z = {0.f, 0.f, 0.f, 0.f};
      acc[mi][ni] = z;
    }

  for (int kt = 0; kt < FFN; kt += 64) {
    // ---- issue all staging loads ----
    float pb[4][4];
    {
      const float* src = b_ptr + (size_t)kt * HID;
#pragma unroll
      for (int j = 0; j < 4; ++j)
        *(float4*)pb[j] = *(const float4*)(src + (size_t)j * HID);
    }
    v8bf pa[4];
    if (avalid) {
      const v8bf* s = (const v8bf*)(a_src + kt);
#pragma unroll
      for (int c = 0; c < 4; ++c) pa[c] = s[c];
    } else {
#pragma unroll
      for (int c = 0; c < 4; ++c) pa[c] = zero_v8bf();
    }
    // ---- convert + LDS write ----
#pragma unroll
    for (int c = 0; c < 4; ++c) *(v8bf*)&sA[swz(ar, ac4 + c)] = pa[c];
#pragma unroll
    for (int i = 0; i < 4; ++i) {
      v4bf v;
#pragma unroll
      for (int j = 0; j < 4; ++j) v[j] = (__bf16)pb[j][i];
      *(v4bf*)&sB[swz(brow0 + i, kg >> 1) + (kg & 1) * 4] = v;
    }
    __syncthreads();

#pragma unroll
    for (int ks = 0; ks < 2; ++ks) {
      v8bf a[4], b[2];
#pragma unroll
      for (int mi = 0; mi < 4; ++mi)
        a[mi] = *(const v8bf*)&sA[swz(wr * 64 + mi * 16 + lrow, ks * 4 + lq)];
#pragma unroll
      for (int ni = 0; ni < 2; ++ni)
        b[ni] = *(const v8bf*)&sB[swz(wf * 32 + ni * 16 + lrow, ks * 4 + lq)];
#pragma unroll
      for (int mi = 0; mi < 4; ++mi)
#pragma unroll
        for (int ni = 0; ni < 2; ++ni)
          acc[mi][ni] = __builtin_amdgcn_mfma_f32_16x16x32_bf16(
              a[mi], b[ni], acc[mi][ni], 0, 0, 0);
    }
    __syncthreads();
  }

  // ---- epilogue: atomicAdd weighted expert output into out ----
#pragma unroll
  for (int mi = 0; mi < 4; ++mi) {
#pragma unroll
    for (int ni = 0; ni < 2; ++ni) {
      const int n = n0 + wf * 32 + ni * 16 + lrow;
#pragma unroll
      for (int r = 0; r < 4; ++r) {
        const int lr = wr * 64 + mi * 16 + lq * 4 + r;
        const int m = m0 + lr;
        if (m < cnt) {
          const int t = sTok[lr];
          atomicAdd(&out[(size_t)t * HID + n], acc[mi][ni][r]);
        }
      }
    }
  }
}

// ---------------------------------------------------------------------------
extern "C" void kernel_launch(void* const* d_in, const int* in_sizes, int n_in,
                              void* d_out, int out_size, void* d_ws, size_t ws_size,
                              hipStream_t stream) {
  const float* hidden = (const float*)d_in[0];
  const float* rw     = (const float*)d_in[1];
  const float* bias   = (const float*)d_in[2];
  const float* w13    = (const float*)d_in[3];
  const float* w2     = (const float*)d_in[4];
  float* out = (float*)d_out;

  char* ws = (char*)d_ws;
  int* counts = (int*)ws;
  int* offsets = (int*)(ws + 64);
  int* pair_token = (int*)(ws + 256);
  float* pair_weight = (float*)(ws + 256 + (size_t)NEXP * TOKENS * 4);
  __bf16* hbf = (__bf16*)(ws + 256 + 2 * (size_t)NEXP * TOKENS * 4);
  __bf16* act = hbf + (size_t)TOKENS * HID;

  hipMemsetAsync(counts, 0, 16 * sizeof(int), stream);
  router_kernel<<<TOKENS, 256, 0, stream>>>(hidden, rw, bias, out, hbf,
                                            counts, pair_token, pair_weight);
  scan_kernel<<<1, 64, 0, stream>>>(counts, offsets);
  // gemm1: 8 xcd x (32 mt x 16 ft) x 2 ehi = 8192 blocks
  gemm1_kernel<<<8192, 256, 0, stream>>>(
      hbf, w13, counts, offsets, pair_token, pair_weight, act);
  // gemm2: 8 xcd x (16 mt x 32 nt) x 2 ehi = 8192 blocks
  gemm2_kernel<<<8192, 256, 0, stream>>>(
      act, w2, counts, offsets, pair_token, out);
}